// Round 26
// baseline (268.542 us; speedup 1.0000x reference)
//
#include <hip/hip_runtime.h>
#include <hip/hip_bf16.h>

typedef __bf16 bf16x8 __attribute__((ext_vector_type(8)));
typedef __bf16 bf16x4 __attribute__((ext_vector_type(4)));
typedef float  f32x4  __attribute__((ext_vector_type(4)));
typedef float  f32x2  __attribute__((ext_vector_type(2)));

#define T_TOK 2048
#define DDIM  1024
#define EDIM  2048
#define NCHUNK 32
#define CKLEN  64

__device__ __forceinline__ f32x2 vfma2(f32x2 a, f32x2 b, f32x2 c)
{
#if __has_builtin(__builtin_elementwise_fma)
    return __builtin_elementwise_fma(a, b, c);
#else
    return (f32x2){fmaf(a.x, b.x, c.x), fmaf(a.y, b.y, c.y)};
#endif
}

// exp(w) for w in [-0.15, 0]: degree-3 Taylor, rel err <= 4e-6.
__device__ __forceinline__ f32x2 exps2(f32x2 w)
{
    const f32x2 C6  = {0.166666667f, 0.166666667f};
    const f32x2 CH  = {0.5f, 0.5f};
    const f32x2 ONE = {1.f, 1.f};
    return vfma2(w, vfma2(w, vfma2(w, C6, CH), ONE), ONE);
}

// Fused DPP 16-lane tree sum (lane 15 of each row gets the row total).
// HAZARD-GUARDED: VALU-write -> DPP-read needs 2 wait states (s_nop 1).
__device__ __forceinline__ float dpp_sum16(float p)
{
    asm volatile(
        "s_nop 1\n\t"
        "v_add_f32 %0, %0, %0 row_shr:1 bound_ctrl:0\n\t"
        "s_nop 1\n\t"
        "v_add_f32 %0, %0, %0 row_shr:2 bound_ctrl:0\n\t"
        "s_nop 1\n\t"
        "v_add_f32 %0, %0, %0 row_shr:4 bound_ctrl:0\n\t"
        "s_nop 1\n\t"
        "v_add_f32 %0, %0, %0 row_shr:8 bound_ctrl:0"
        : "+v"(p));
    return p;
}

// ---------------------------------------------------------------- batched weight prep
// mode 0: dst row = src col c.  mode 1: row = 32*(c>>4)+(c&15) (gate interleave).
// mode 2: row = 32*(c>>4)+16+(c&15) (up interleave).
struct TJob { const float* src; __bf16* dst; int R, C, S, tilesX, tileOff, mode; };
struct TJobs8 { TJob j[8]; };

__global__ __launch_bounds__(256)
void wprep_kernel(TJobs8 jobs)
{
    int tile = blockIdx.x;
    int ji = 0;
#pragma unroll
    for (int k = 1; k < 8; ++k) if (tile >= jobs.j[k].tileOff) ji = k;
    const TJob jb = jobs.j[ji];
    int rel = tile - jb.tileOff;
    int bx = rel % jb.tilesX, by = rel / jb.tilesX;
    __shared__ float tilebuf[32][33];
    const int tc0 = bx * 32, tr0 = by * 32;
    const int tx = threadIdx.x & 31, ty = threadIdx.x >> 5;
#pragma unroll
    for (int p = 0; p < 4; ++p) {
        int rl = ty + p * 8;
        tilebuf[rl][tx] = jb.src[(size_t)(tr0 + rl) * jb.S + tc0 + tx];
    }
    __syncthreads();
#pragma unroll
    for (int p = 0; p < 4; ++p) {
        int cl = ty + p * 8;
        float v = tilebuf[tx][cl];
        int c = tc0 + cl, r = tr0 + tx;
        int dr = (jb.mode == 0) ? c
               : ((c >> 4) * 32 + (c & 15) + ((jb.mode == 2) ? 16 : 0));
        jb.dst[(size_t)dr * jb.R + r] = (__bf16)v;
    }
}

// ---------------------------------------------------------------- rmsnorm
__global__ __launch_bounds__(256)
void rmsnorm_kernel(const float* __restrict__ x, const float* __restrict__ w,
                    __bf16* __restrict__ out)
{
    const int row = blockIdx.x;
    const int t = threadIdx.x;
    float4 v = ((const float4*)(x + (size_t)row * DDIM))[t];
    float ss = v.x * v.x + v.y * v.y + v.z * v.z + v.w * v.w;
#pragma unroll
    for (int m = 32; m; m >>= 1) ss += __shfl_xor(ss, m);
    __shared__ float red[4];
    if ((t & 63) == 0) red[t >> 6] = ss;
    __syncthreads();
    float scale = rsqrtf((red[0] + red[1] + red[2] + red[3]) * (1.f / DDIM) + 1e-5f);
    float4 wv = ((const float4*)w)[t];
    __bf16* o = out + (size_t)row * DDIM + t * 4;
    o[0] = (__bf16)(v.x * scale * wv.x);
    o[1] = (__bf16)(v.y * scale * wv.y);
    o[2] = (__bf16)(v.z * scale * wv.z);
    o[3] = (__bf16)(v.w * scale * wv.w);
}

// ---------------------------------------------------------------- conv+silu (+xcT)
__global__ __launch_bounds__(256)
void conv_silu_xt_kernel(const __bf16* __restrict__ xz, const float* __restrict__ W,
                         const float* __restrict__ b, __bf16* __restrict__ xc,
                         __bf16* __restrict__ xcT)
{
    __shared__ __bf16 s_t[32][72];
    const int tid = threadIdx.x;
    const int e0 = blockIdx.x * 64, t0 = blockIdx.y * 32;
    const int tl = tid >> 3, e8 = (tid & 7) * 8;
    const int t = t0 + tl;
    float acc[8];
    {
        float4 b0 = *(const float4*)(b + e0 + e8);
        float4 b1 = *(const float4*)(b + e0 + e8 + 4);
        acc[0] = b0.x; acc[1] = b0.y; acc[2] = b0.z; acc[3] = b0.w;
        acc[4] = b1.x; acc[5] = b1.y; acc[6] = b1.z; acc[7] = b1.w;
    }
#pragma unroll
    for (int k = 0; k < 4; ++k) {
        int tt = t - 1 + k;
        if (tt >= 0 && tt < T_TOK) {
            bf16x8 v = *(const bf16x8*)(xz + (size_t)tt * EDIM + e0 + e8);
            float4 w0 = *(const float4*)(W + k * EDIM + e0 + e8);
            float4 w1 = *(const float4*)(W + k * EDIM + e0 + e8 + 4);
            acc[0] += (float)v[0] * w0.x; acc[1] += (float)v[1] * w0.y;
            acc[2] += (float)v[2] * w0.z; acc[3] += (float)v[3] * w0.w;
            acc[4] += (float)v[4] * w1.x; acc[5] += (float)v[5] * w1.y;
            acc[6] += (float)v[6] * w1.z; acc[7] += (float)v[7] * w1.w;
        }
    }
    bf16x8 o;
#pragma unroll
    for (int j = 0; j < 8; ++j) {
        float s = acc[j];
        o[j] = (__bf16)(s / (1.f + __expf(-s)));
    }
    *(bf16x8*)(xc + (size_t)t * EDIM + e0 + e8) = o;
    *(bf16x8*)&s_t[tl][e8] = o;
    __syncthreads();
    {
        int el = tid >> 2, t8 = (tid & 3) * 8;
        bf16x8 o2;
#pragma unroll
        for (int j = 0; j < 8; ++j) o2[j] = s_t[t8 + j][el];
        *(bf16x8*)(xcT + (size_t)(e0 + el) * T_TOK + t0 + t8) = o2;
    }
}

// ---------------------------------------------------------------- scan
// bc layout (f32, plane-split): bc[t*128 + n] = B[t,n], bc[t*128+64+n] = C[t,n].

// Pass 1: block = 8 waves, 32 channels, one chunk; B-plane only staged.
// Wave w: 4 channels (w*4+g, g=lane>>4), 16 lanes/channel, 4 states/lane.
__global__ __launch_bounds__(512)
void scan1_kernel(const float* __restrict__ dtT, const __bf16* __restrict__ xcT,
                  const float* __restrict__ bc2, const float* __restrict__ A_log,
                  float* __restrict__ hend, float* __restrict__ dAp)
{
    __shared__ float  s_b[CKLEN * 64];     // 16 KB (B-plane)
    __shared__ float  s_dt[32][68];        // padded rows
    __shared__ __bf16 s_x[32][72];         // padded rows
    const int tid = threadIdx.x;
    const int lane = tid & 63, w = tid >> 6;
    const int g = lane >> 4, i = lane & 15;
    const int ck = blockIdx.x & (NCHUNK - 1);
    const int eg = (blockIdx.x >> 5) * 32;

    {
#pragma unroll
        for (int r = 0; r < 2; ++r) {
            int linear = r * 512 + tid;
            int t = linear >> 4, k = linear & 15;
            *(float4*)&s_b[t * 64 + 4 * k] =
                *(const float4*)(bc2 + (size_t)(ck * CKLEN + t) * 128 + 4 * k);
        }
        { int ch = tid >> 4, k = tid & 15;
          *(float4*)&s_dt[ch][4 * k] =
              *(const float4*)(dtT + (size_t)(eg + ch) * T_TOK + ck * CKLEN + 4 * k); }
        if (tid < 256) { int ch = tid >> 3, k = tid & 7;
          *(bf16x8*)&s_x[ch][8 * k] =
              *(const bf16x8*)(xcT + (size_t)(eg + ch) * T_TOK + ck * CKLEN + 8 * k); }
    }
    __syncthreads();

    const int ch = w * 4 + g;
    const int e = eg + ch;
    float4 al4 = *(const float4*)(A_log + 4 * i);
    const f32x2 A01 = {-__expf(al4.x), -__expf(al4.y)};
    const f32x2 A23 = {-__expf(al4.z), -__expf(al4.w)};
    f32x2 h01 = {0.f, 0.f}, h23 = {0.f, 0.f};
    float D = 0.f;

#pragma unroll 2
    for (int t0 = 0; t0 < CKLEN; t0 += 8) {
        float4 da = *(const float4*)&s_dt[ch][t0];
        float4 db = *(const float4*)&s_dt[ch][t0 + 4];
        bf16x8 x8 = *(const bf16x8*)&s_x[ch][t0];
        float dtv[8] = {da.x, da.y, da.z, da.w, db.x, db.y, db.z, db.w};
#pragma unroll
        for (int j = 0; j < 8; ++j) {
            float4 b0 = *(const float4*)&s_b[(t0 + j) * 64 + 4 * i];
            float dt = dtv[j];
            float u = dt * (float)x8[j];
            f32x2 dt2 = {dt, dt};
            f32x2 dA01 = exps2(dt2 * A01);
            f32x2 dA23 = exps2(dt2 * A23);
            f32x2 uu = {u, u};
            h01 = vfma2(dA01, h01, uu * (f32x2){b0.x, b0.y});
            h23 = vfma2(dA23, h23, uu * (f32x2){b0.z, b0.w});
            D += dt;
        }
    }
    const float L2E = 1.44269504f;
    size_t idx = ((size_t)e * NCHUNK + ck) * 64 + 4 * i;
    *(float4*)(hend + idx) = make_float4(h01.x, h01.y, h23.x, h23.y);
    *(float4*)(dAp + idx)  = make_float4(__builtin_amdgcn_exp2f(A01.x * L2E * D),
                                         __builtin_amdgcn_exp2f(A01.y * L2E * D),
                                         __builtin_amdgcn_exp2f(A23.x * L2E * D),
                                         __builtin_amdgcn_exp2f(A23.y * L2E * D));
}

// Mid: serial scan over chunk summaries -> h_start per chunk, IN PLACE over hend.
__global__ __launch_bounds__(256)
void scan_mid_kernel(float* __restrict__ hend_h0, const float* __restrict__ dAp)
{
    int gid = blockIdx.x * 256 + threadIdx.x;     // over E*64
    int e = gid >> 6, n = gid & 63;
    float h = 0.f;
#pragma unroll
    for (int ck = 0; ck < NCHUNK; ++ck) {
        size_t idx = ((size_t)e * NCHUNK + ck) * 64 + n;
        float he = hend_h0[idx];
        float P  = dAp[idx];
        hend_h0[idx] = h;
        h = P * h + he;
    }
}

// Pass 2: block = 8 waves, 32 channels, one chunk; B/C planes staged separately.
__global__ __launch_bounds__(512)
void scan2_kernel(const float* __restrict__ dtT, const __bf16* __restrict__ xcT,
                  const __bf16* __restrict__ szT, const float* __restrict__ bc2,
                  const float* __restrict__ A_log, const float* __restrict__ h0s,
                  __bf16* __restrict__ y)
{
    __shared__ float  s_bp[CKLEN * 64];    // 16 KB (B-plane)
    __shared__ float  s_cp[CKLEN * 64];    // 16 KB (C-plane)
    __shared__ float  s_dt[32][68];        // padded rows
    __shared__ __bf16 s_x[32][72];         // padded rows
    __shared__ __bf16 s_y[CKLEN][36];      // padded, t-major tile
    const int tid = threadIdx.x;
    const int lane = tid & 63, w = tid >> 6;
    const int g = lane >> 4, i = lane & 15;
    const int ck = blockIdx.x & (NCHUNK - 1);
    const int eg = (blockIdx.x >> 5) * 32;

    {
#pragma unroll
        for (int r = 0; r < 2; ++r) {
            int linear = r * 512 + tid;
            int t = linear >> 4, k = linear & 15;
            const float* src = bc2 + (size_t)(ck * CKLEN + t) * 128 + 4 * k;
            *(float4*)&s_bp[t * 64 + 4 * k] = *(const float4*)src;
            *(float4*)&s_cp[t * 64 + 4 * k] = *(const float4*)(src + 64);
        }
        { int ch = tid >> 4, k = tid & 15;
          *(float4*)&s_dt[ch][4 * k] =
              *(const float4*)(dtT + (size_t)(eg + ch) * T_TOK + ck * CKLEN + 4 * k); }
        if (tid < 256) { int ch = tid >> 3, k = tid & 7;
          *(bf16x8*)&s_x[ch][8 * k] =
              *(const bf16x8*)(xcT + (size_t)(eg + ch) * T_TOK + ck * CKLEN + 8 * k); }
    }
    __syncthreads();

    const int ch = w * 4 + g;
    const int e = eg + ch;
    float4 al4 = *(const float4*)(A_log + 4 * i);
    const f32x2 A01 = {-__expf(al4.x), -__expf(al4.y)};
    const f32x2 A23 = {-__expf(al4.z), -__expf(al4.w)};
    float4 hh = *(const float4*)(h0s + ((size_t)e * NCHUNK + ck) * 64 + 4 * i);
    f32x2 h01 = {hh.x, hh.y}, h23 = {hh.z, hh.w};

#pragma unroll 2
    for (int t0 = 0; t0 < CKLEN; t0 += 8) {
        float4 da = *(const float4*)&s_dt[ch][t0];
        float4 db = *(const float4*)&s_dt[ch][t0 + 4];
        bf16x8 x8 = *(const bf16x8*)&s_x[ch][t0];
        float dtv[8] = {da.x, da.y, da.z, da.w, db.x, db.y, db.z, db.w};
#pragma unroll
        for (int j = 0; j < 8; ++j) {
            float4 b0 = *(const float4*)&s_bp[(t0 + j) * 64 + 4 * i];
            float4 c0 = *(const float4*)&s_cp[(t0 + j) * 64 + 4 * i];
            float dt = dtv[j];
            float u = dt * (float)x8[j];
            f32x2 dt2 = {dt, dt};
            f32x2 dA01 = exps2(dt2 * A01);
            f32x2 dA23 = exps2(dt2 * A23);
            f32x2 uu = {u, u};
            h01 = vfma2(dA01, h01, uu * (f32x2){b0.x, b0.y});
            h23 = vfma2(dA23, h23, uu * (f32x2){b0.z, b0.w});
            f32x2 pp = h01 * (f32x2){c0.x, c0.y};
            pp = vfma2(h23, (f32x2){c0.z, c0.w}, pp);
            float p = pp.x + pp.y;
            p = dpp_sum16(p);
            if (i == 15) s_y[t0 + j][ch] = (__bf16)p;
        }
    }
    __syncthreads();

    {
        int tt = tid >> 3, q = tid & 7;
        bf16x4 o;
#pragma unroll
        for (int d = 0; d < 4; ++d) {
            float zv = (float)szT[(size_t)(eg + 4 * q + d) * T_TOK + ck * CKLEN + tt];
            o[d] = (__bf16)((float)s_y[tt][4 * q + d] * zv);
        }
        *(bf16x4*)(y + (size_t)(ck * CKLEN + tt) * EDIM + eg + 4 * q) = o;
    }
}

// ---------------------------------------------------------------- GEMM common
__device__ __forceinline__ void glds16(const __bf16* g, __bf16* l)
{
    __builtin_amdgcn_global_load_lds(
        (const __attribute__((address_space(1))) unsigned*)g,
        (__attribute__((address_space(3))) unsigned*)l, 16, 0, 0);
}

template<int EPI>
__device__ __forceinline__ void gemm_epilogue(
    const f32x4& a, int row, int col, int N,
    void* Cout, void* Cout2, const float* res)
{
    if (EPI == 1) {
#pragma unroll
        for (int i = 0; i < 4; ++i)
            ((__bf16*)Cout)[(size_t)(row + i) * N + col] = (__bf16)a[i];
    } else if (EPI == 2) {
#pragma unroll
        for (int i = 0; i < 4; ++i) {
            size_t off = (size_t)(row + i) * N + col;
            ((float*)Cout)[off] = a[i] + res[off];
        }
    } else if (EPI == 3) {
        if (col < 2048) {
            float bias = res[col];
            float4 v;
            float* vv = (float*)&v;
#pragma unroll
            for (int i = 0; i < 4; ++i) {
                float s = a[i] + bias;
                s = (s > 20.f) ? s : log1pf(__expf(s));
                vv[i] = fminf(fmaxf(s, 0.001f), 0.1f);
            }
            *(float4*)((float*)Cout + (size_t)col * T_TOK + row) = v;
        } else {
#pragma unroll
            for (int i = 0; i < 4; ++i)
                ((float*)Cout2)[(size_t)(row + i) * 128 + (col - 2048)] = a[i];
        }
    } else if (EPI == 4) {
        if (col < 2048) {
#pragma unroll
            for (int i = 0; i < 4; ++i)
                ((__bf16*)Cout)[(size_t)(row + i) * EDIM + col] = (__bf16)a[i];
        } else {
            bf16x4 v;
#pragma unroll
            for (int i = 0; i < 4; ++i) {
                float s = a[i];
                v[i] = (__bf16)(s / (1.f + __expf(-s)));
            }
            *(bf16x4*)((__bf16*)Cout2 + (size_t)(col - 2048) * T_TOK + row) = v;
        }
    }
}

// 4-wave GEMM: 64 x TN tile (TN = 64 or 128), BK=64, 3-buffer depth-2
// pipeline with counted vmcnt + raw s_barrier (T3/T4): tile k's loads are
// waited with vmcnt(LPW) so tile k+1's stay in flight across the barrier.
// 8-chunk XOR-swizzled LDS.  SWZ<1>: XCD-contiguous block remap.
template<int EPI, int TN, int SWZ>
__global__ __launch_bounds__(256)
void gemm_kernel(const __bf16* __restrict__ A, const __bf16* __restrict__ Bt,
                 void* __restrict__ Cout, void* __restrict__ Cout2,
                 const float* __restrict__ res, int M, int N, int K)
{
    constexpr int NF = TN / 32;            // n-frags per wave
    constexpr int BQ = TN / 32;            // B glds16 per wave per stage
    constexpr int LPW = 2 + BQ;            // loads per wave per stage
    __shared__ __bf16 sAl[3 * 64 * 64];    // 24 KB
    __shared__ __bf16 sBl[3 * TN * 64];    // 24 or 48 KB
    const int t = threadIdx.x;
    const int wave = t >> 6, lane = t & 63;
    int bx = blockIdx.x, by = blockIdx.y;
    if (SWZ) {
        int nwg = gridDim.x * gridDim.y;
        int bid = by * gridDim.x + bx;
        int cpx = nwg >> 3;
        int swz = (bid & 7) * cpx + (bid >> 3);
        bx = swz % gridDim.x;
        by = swz / gridDim.x;
    }
    const int brow = by * 64, bcol = bx * TN;
    const int wr = (wave >> 1) * 32, wc = (wave & 1) * (TN / 2);
    f32x4 acc[2][NF] = {};

    const int rl8 = lane >> 3;
    const int ck8 = (lane & 7) ^ rl8;
    const __bf16* gA = A  + (size_t)(brow + wave * 16 + rl8) * K + ck8 * 8;
    const __bf16* gB = Bt + (size_t)(bcol + wave * (TN / 4) + rl8) * K + ck8 * 8;

    auto stage = [&](int buf, int k0) {
        __bf16* ba = sAl + buf * (64 * 64) + (wave * 16) * 64;
        __bf16* bb = sBl + buf * (TN * 64) + (wave * (TN / 4)) * 64;
#pragma unroll
        for (int q = 0; q < 2; ++q)
            glds16(gA + (size_t)(q * 8) * K + k0, ba + q * 8 * 64);
#pragma unroll
        for (int q = 0; q < BQ; ++q)
            glds16(gB + (size_t)(q * 8) * K + k0, bb + q * 8 * 64);
    };

    const int nk = K >> 6;                 // K/64 steps (>= 16 for all shapes)
    stage(0, 0);
    stage(1, 64);
    for (int kk = 0; kk < nk; ++kk) {
        // wait for tile kk's loads; tile kk+1's LPW loads may stay in flight
        if (kk + 1 < nk)
            asm volatile("s_waitcnt vmcnt(%0)" :: "n"(LPW) : "memory");
        else
            asm volatile("s_waitcnt vmcnt(0)" ::: "memory");
        __builtin_amdgcn_sched_barrier(0);
        __builtin_amdgcn_s_barrier();      // all waves' tile-kk data visible
        const int cb = kk % 3;
        const __bf16* At = sAl + cb * (64 * 64);
        const __bf16* Btl = sBl + cb * (TN * 64);
#pragma unroll
        for (int ks = 0; ks < 2; ++ks) {
            const int rc = (((ks * 4 + (lane >> 4)) ^ (lane & 7))) * 8;
            bf16x8 af[2], bg[NF];
#pragma unroll
            for (int m = 0; m < 2; ++m)
                af[m] = *(const bf16x8*)&At[(wr + m * 16 + (lane & 15)) * 64 + rc];
#pragma unroll
            for (int n = 0; n < NF; ++n)
                bg[n] = *(const bf16x8*)&Btl[(wc + n * 16 + (lane & 15)) * 64 + rc];
#pragma unroll
            for (int m = 0; m < 2; ++m)
#pragma unroll
                for (int n = 0; n < NF; ++n)
                    acc[m][n] = __builtin_amdgcn_mfma_f32_16x16x32_bf16(
                        af[m], bg[n], acc[m][n], 0, 0, 0);
        }
        // prefetch tile kk+2 into buf (kk+2)%3 = (kk-1)%3, whose readers all
        // passed the barrier above (they finished compute(kk-1) before it).
        if (kk + 2 < nk) stage((kk + 2) % 3, (kk + 2) * 64);
    }

    const int c_l = lane & 15, r_l = (lane >> 4) * 4;
#pragma unroll
    for (int m = 0; m < 2; ++m)
#pragma unroll
        for (int n = 0; n < NF; ++n)
            gemm_epilogue<EPI>(acc[m][n], brow + wr + m * 16 + r_l,
                               bcol + wc + n * 16 + c_l, N, Cout, Cout2, res);
}

// 8-wave big GEMM: 128 x 128 tile, BK=64, 2-phase, XOR chunk-swizzled LDS.
// 64 KB LDS -> 2 blocks/CU (16 waves) so barrier vmcnt drains cross-hide.
// Wave layout 2x4: wave-tile 64x32 (acc[4][2], 16 MFMA/wave/K-step).
// EPI 5: fused GLU (16-col interleaved gate/up weights): frag pair (0,1)
// within a wave = gate/up cols for the same 32-col group.
// SWZ<1>: XCD-contiguous block remap (grid mult of 8).
template<int EPI, int SWZ>
__global__ __launch_bounds__(512)
void gemm_big(const __bf16* __restrict__ A, const __bf16* __restrict__ Bt,
              void* __restrict__ Cout, void* __restrict__ Cout2,
              const float* __restrict__ res, int M, int N, int K)
{
    __shared__ __bf16 sAl[2 * 128 * 64];   // 32 KB
    __shared__ __bf16 sBl[2 * 128 * 64];   // 32 KB
    const int t = threadIdx.x;
    const int w = t >> 6, lane = t & 63;
    int bx = blockIdx.x, by = blockIdx.y;
    if (SWZ) {
        int nwg = gridDim.x * gridDim.y;
        int bid = by * gridDim.x + bx;
        int cpx = nwg >> 3;
        int swz = (bid & 7) * cpx + (bid >> 3);
        bx = swz % gridDim.x;
        by = swz / gridDim.x;
    }
    const int brow = by * 128, bcol = bx * 128;
    const int wr = (w >> 2) * 64, wc = (w & 3) * 32;
    f32x4 acc[4][2] = {};

    const int rl8 = lane >> 3;
    const int ck8 = (lane & 7) ^ rl8;
    const __bf16* gA = A  + (size_t)(brow + w * 16 + rl8) * K + ck8 * 8;
    const __bf16* gB = Bt + (size_t)(bcol + w * 16 + rl8) * K + ck8 * 8;

    auto stage = [&](int buf, int k0) {
        __bf16* ba = sAl + buf * (128 * 64) + (w * 16) * 64;
        __bf16* bb = sBl + buf * (128 * 64) + (w * 16) * 64;
#pragma unroll
        for (int q = 0; q < 2; ++q)
            glds16(gA + (size_t)(q * 8) * K + k0, ba + q * 8 * 64);
#pragma unroll
        for (int q = 0; q < 2; ++q)
            glds16(gB + (size_t)(q * 8) * K + k0, bb + q * 8 * 64);
    };

    stage(0, 0);
    int cur = 0;
    for (int k0 = 0; k0 < K; k0 += 64) {
        __syncthreads();
        if (k0 + 64 < K) stage(cur ^ 1, k0 + 64);
        const __bf16* At = sAl + cur * (128 * 64);
        const __bf16* Btl = sBl + cur * (128 * 64);
#pragma unroll
        for (int ks = 0; ks < 2; ++ks) {
            const int rchk = (((ks * 4 + (lane >> 4)) ^ (lane & 7))) * 8;
            bf16x8 af[4], bg[2];
#pragma unroll
            for (int m = 0; m < 4; ++m)
                af[m] = *(const bf16x8*)&At[(wr + m * 16 + (lane & 15)) * 64 + rchk];
#pragma unroll
            for (int n = 0; n < 2; ++n)
                bg[n] = *(const bf16x8*)&Btl[(wc + n * 16 + (lane & 15)) * 64 + rchk];
#pragma unroll
            for (int m = 0; m < 4; ++m)
#pragma unroll
                for (int n = 0; n < 2; ++n)
                    acc[m][n] = __builtin_amdgcn_mfma_f32_16x16x32_bf16(
                        af[m], bg[n], acc[m][n], 0, 0, 0);
        }
        cur ^= 1;
    }

    const int c_l = lane & 15, r_l = (lane >> 4) * 4;
    if constexpr (EPI == 5) {
#pragma unroll
        for (int m = 0; m < 4; ++m) {
            int row = brow + wr + m * 16 + r_l;
            int fcol = (((bcol + wc) >> 5) << 4) + c_l;
#pragma unroll
            for (int i = 0; i < 4; ++i) {
                float gg = acc[m][0][i];
                float uu = acc[m][1][i];
                ((__bf16*)Cout)[(size_t)(row + i) * 2048 + fcol] =
                    (__bf16)(gg / (1.f + __expf(-gg)) * uu);
            }
        }
    } else {
#pragma unroll
        for (int m = 0; m < 4; ++m)
#pragma unroll
            for (int n = 0; n < 2; ++n)
                gemm_epilogue<EPI>(acc[m][n], brow + wr + m * 16 + r_l,
                                   bcol + wc + n * 16 + c_l, N, Cout, Cout2, res);
    }
}

// ---------------------------------------------------------------- launch
extern "C" void kernel_launch(void* const* d_in, const int* in_sizes, int n_in,
                              void* d_out, int out_size, void* d_ws, size_t ws_size,
                              hipStream_t stream)
{
    (void)in_sizes; (void)n_in; (void)out_size; (void)ws_size;
    const float* x     = (const float*)d_in[0];
    const float* inw   = (const float*)d_in[1];
    const float* ffnw  = (const float*)d_in[2];
    const float* inpW  = (const float*)d_in[3];
    const float* convW = (const float*)d_in[4];
    const float* convB = (const float*)d_in[5];
    const float* dtW   = (const float*)d_in[6];
    const float* dtB   = (const float*)d_in[7];
    const float* BW    = (const float*)d_in[8];
    const float* CW    = (const float*)d_in[9];
    const float* Alog  = (const float*)d_in[10];
    const float* outpW = (const float*)d_in[11];
    const float* gateW = (const float*)d_in[12];
    const float* upW   = (const float*)d_in[13];
    const float* downW = (const float*)d_in[14];
    float* out = (float*)d_out;

    char* p = (char*)d_ws;
    auto alloc = [&](size_t n) { char* q = p; p += (n + 255) & ~(size_t)255; return q; };
    __bf16* wt_inproj = (__bf16*)alloc(4096ull * 1024 * 2);
    __bf16* wt_dtbc   = (__bf16*)alloc(2176ull * 2048 * 2);  // rows: 0-2047 dt, 2048-2111 B, 2112-2175 C
    __bf16* wt_outp   = (__bf16*)alloc(1024ull * 2048 * 2);
    __bf16* wt_gu     = (__bf16*)alloc(4096ull * 1024 * 2);  // 16-col interleaved gate/up
    __bf16* wt_down   = (__bf16*)alloc(1024ull * 2048 * 2);
    __bf16* normed    = (__bf16*)alloc(2048ull * 1024 * 2);  // reused as n2
    __bf16* xz        = (__bf16*)alloc(2048ull * 2048 * 2);  // x_z half of in_proj
    __bf16* gu_buf    = (__bf16*)alloc(2048ull * 4096 * 2);  // dAp scratch
    __bf16* xc        = (__bf16*)alloc(2048ull * 2048 * 2);  // conv out, reused as y
    float*  scratch16 = (float*)alloc(2048ull * 2048 * 4);   // hend/h0 then ffnmid
    float*  bc        = (float*)alloc(2048ull * 128 * 4);
    float*  dtT       = (float*)alloc(2048ull * 2048 * 4);
    __bf16* xcT       = (__bf16*)alloc(2048ull * 2048 * 2);
    __bf16* szT       = (__bf16*)alloc(2048ull * 2048 * 2);
    float*  x2        = (float*)alloc(2048ull * 1024 * 4);

    dim3 B256(256);
    // batched weight prep (one dispatch); gate/up interleaved at 16-col granularity
    {
        TJobs8 tj;
        int off = 0, ji = 0;
        auto addjob = [&](const float* s, __bf16* d, int R, int C, int S, int mode) {
            tj.j[ji++] = TJob{s, d, R, C, S, C / 32, off, mode};
            off += (C / 32) * (R / 32);
        };
        addjob(inpW,  wt_inproj, 1024, 4096, 4096, 0);
        addjob(dtW,   wt_dtbc,   2048, 2048, 2048, 0);
        addjob(BW,    wt_dtbc + 2048ull * 2048, 2048, 64, 64, 0);
        addjob(CW,    wt_dtbc + 2112ull * 2048, 2048, 64, 64, 0);
        addjob(outpW, wt_outp,   2048, 1024, 1024, 0);
        addjob(gateW, wt_gu,     1024, 2048, 2048, 1);
        addjob(upW,   wt_gu,     1024, 2048, 2048, 2);
        addjob(downW, wt_down,   2048, 1024, 1024, 0);
        wprep_kernel<<<dim3(off), B256, 0, stream>>>(tj);
    }

    // normed = rmsnorm(x, inw)
    rmsnorm_kernel<<<dim3(2048), B256, 0, stream>>>(x, inw, normed);
    // in_proj: xz (t-major bf16) + szT (silu'd z, channel-major)
    gemm_big<4, 1><<<dim3(32, 16), dim3(512), 0, stream>>>(normed, wt_inproj, xz, szT, nullptr, 2048, 4096, 1024);
    // xc = silu(conv(xz) + b), also writes xcT (channel-major) in one pass
    conv_silu_xt_kernel<<<dim3(32, 64), B256, 0, stream>>>(xz, convW, convB, xc, xcT);
    // fused dt+bc: dtT (softplus'd, channel-major f32) + bc (t-major f32, planes)
    gemm_kernel<3, 128, 1><<<dim3(17, 32), B256, 0, stream>>>(xc, wt_dtbc, dtT, bc, dtB, 2048, 2176, 2048);

    // chunked SSM scan
    float* hend = scratch16;                      // 16 MB (E*32*64 f32)
    float* dAp  = (float*)gu_buf;                 // 16 MB
    scan1_kernel<<<dim3(2048), dim3(512), 0, stream>>>(dtT, xcT, bc, Alog, hend, dAp);
    scan_mid_kernel<<<dim3(512), B256, 0, stream>>>(hend, dAp);
    __bf16* y = xc;                               // xc dead after dt GEMM
    scan2_kernel<<<dim3(2048), dim3(512), 0, stream>>>(dtT, xcT, szT, bc, Alog, hend, y);

    // x2 = x + y @ out_proj
    gemm_kernel<2, 64, 1><<<dim3(16, 32), B256, 0, stream>>>(y, wt_outp, x2, nullptr, x, 2048, 1024, 2048);
    // n2 = rmsnorm(x2, ffnw)
    rmsnorm_kernel<<<dim3(2048), B256, 0, stream>>>(x2, ffnw, normed);
    // ffnmid = silu(n2@gate) * (n2@up)  -- fused GLU epilogue
    __bf16* ffnmid = (__bf16*)scratch16;
    gemm_big<5, 1><<<dim3(32, 16), dim3(512), 0, stream>>>(normed, wt_gu, ffnmid, nullptr, nullptr, 2048, 4096, 1024);
    // out = x2 + ffnmid @ down
    gemm_kernel<2, 64, 1><<<dim3(16, 32), B256, 0, stream>>>(ffnmid, wt_down, out, nullptr, x2, 2048, 1024, 2048);
}

// Round 27
// 268.208 us; speedup vs baseline: 1.0012x; 1.0012x over previous
//
#include <hip/hip_runtime.h>
#include <hip/hip_bf16.h>

typedef __bf16 bf16x8 __attribute__((ext_vector_type(8)));
typedef __bf16 bf16x4 __attribute__((ext_vector_type(4)));
typedef float  f32x4  __attribute__((ext_vector_type(4)));
typedef float  f32x2  __attribute__((ext_vector_type(2)));

#define T_TOK 2048
#define DDIM  1024
#define EDIM  2048
#define NCHUNK 32
#define CKLEN  64

__device__ __forceinline__ f32x2 vfma2(f32x2 a, f32x2 b, f32x2 c)
{
#if __has_builtin(__builtin_elementwise_fma)
    return __builtin_elementwise_fma(a, b, c);
#else
    return (f32x2){fmaf(a.x, b.x, c.x), fmaf(a.y, b.y, c.y)};
#endif
}

// exp(w) for w in [-0.15, 0]: degree-3 Taylor, rel err <= 4e-6.
__device__ __forceinline__ f32x2 exps2(f32x2 w)
{
    const f32x2 C6  = {0.166666667f, 0.166666667f};
    const f32x2 CH  = {0.5f, 0.5f};
    const f32x2 ONE = {1.f, 1.f};
    return vfma2(w, vfma2(w, vfma2(w, C6, CH), ONE), ONE);
}

// Fused DPP 16-lane tree sum (lane 15 of each row gets the row total).
// HAZARD-GUARDED: VALU-write -> DPP-read needs 2 wait states (s_nop 1).
__device__ __forceinline__ float dpp_sum16(float p)
{
    asm volatile(
        "s_nop 1\n\t"
        "v_add_f32 %0, %0, %0 row_shr:1 bound_ctrl:0\n\t"
        "s_nop 1\n\t"
        "v_add_f32 %0, %0, %0 row_shr:2 bound_ctrl:0\n\t"
        "s_nop 1\n\t"
        "v_add_f32 %0, %0, %0 row_shr:4 bound_ctrl:0\n\t"
        "s_nop 1\n\t"
        "v_add_f32 %0, %0, %0 row_shr:8 bound_ctrl:0"
        : "+v"(p));
    return p;
}

// ---------------------------------------------------------------- batched weight prep
// mode 0: dst row = src col c.  mode 1: row = 32*(c>>4)+(c&15) (gate interleave).
// mode 2: row = 32*(c>>4)+16+(c&15) (up interleave).
struct TJob { const float* src; __bf16* dst; int R, C, S, tilesX, tileOff, mode; };
struct TJobs8 { TJob j[8]; };

__global__ __launch_bounds__(256)
void wprep_kernel(TJobs8 jobs)
{
    int tile = blockIdx.x;
    int ji = 0;
#pragma unroll
    for (int k = 1; k < 8; ++k) if (tile >= jobs.j[k].tileOff) ji = k;
    const TJob jb = jobs.j[ji];
    int rel = tile - jb.tileOff;
    int bx = rel % jb.tilesX, by = rel / jb.tilesX;
    __shared__ float tilebuf[32][33];
    const int tc0 = bx * 32, tr0 = by * 32;
    const int tx = threadIdx.x & 31, ty = threadIdx.x >> 5;
#pragma unroll
    for (int p = 0; p < 4; ++p) {
        int rl = ty + p * 8;
        tilebuf[rl][tx] = jb.src[(size_t)(tr0 + rl) * jb.S + tc0 + tx];
    }
    __syncthreads();
#pragma unroll
    for (int p = 0; p < 4; ++p) {
        int cl = ty + p * 8;
        float v = tilebuf[tx][cl];
        int c = tc0 + cl, r = tr0 + tx;
        int dr = (jb.mode == 0) ? c
               : ((c >> 4) * 32 + (c & 15) + ((jb.mode == 2) ? 16 : 0));
        jb.dst[(size_t)dr * jb.R + r] = (__bf16)v;
    }
}

// ---------------------------------------------------------------- rmsnorm
__global__ __launch_bounds__(256)
void rmsnorm_kernel(const float* __restrict__ x, const float* __restrict__ w,
                    __bf16* __restrict__ out)
{
    const int row = blockIdx.x;
    const int t = threadIdx.x;
    float4 v = ((const float4*)(x + (size_t)row * DDIM))[t];
    float ss = v.x * v.x + v.y * v.y + v.z * v.z + v.w * v.w;
#pragma unroll
    for (int m = 32; m; m >>= 1) ss += __shfl_xor(ss, m);
    __shared__ float red[4];
    if ((t & 63) == 0) red[t >> 6] = ss;
    __syncthreads();
    float scale = rsqrtf((red[0] + red[1] + red[2] + red[3]) * (1.f / DDIM) + 1e-5f);
    float4 wv = ((const float4*)w)[t];
    __bf16* o = out + (size_t)row * DDIM + t * 4;
    o[0] = (__bf16)(v.x * scale * wv.x);
    o[1] = (__bf16)(v.y * scale * wv.y);
    o[2] = (__bf16)(v.z * scale * wv.z);
    o[3] = (__bf16)(v.w * scale * wv.w);
}

// ---------------------------------------------------------------- conv+silu (+xcT)
__global__ __launch_bounds__(256)
void conv_silu_xt_kernel(const __bf16* __restrict__ xz, const float* __restrict__ W,
                         const float* __restrict__ b, __bf16* __restrict__ xc,
                         __bf16* __restrict__ xcT)
{
    __shared__ __bf16 s_t[32][72];
    const int tid = threadIdx.x;
    const int e0 = blockIdx.x * 64, t0 = blockIdx.y * 32;
    const int tl = tid >> 3, e8 = (tid & 7) * 8;
    const int t = t0 + tl;
    float acc[8];
    {
        float4 b0 = *(const float4*)(b + e0 + e8);
        float4 b1 = *(const float4*)(b + e0 + e8 + 4);
        acc[0] = b0.x; acc[1] = b0.y; acc[2] = b0.z; acc[3] = b0.w;
        acc[4] = b1.x; acc[5] = b1.y; acc[6] = b1.z; acc[7] = b1.w;
    }
#pragma unroll
    for (int k = 0; k < 4; ++k) {
        int tt = t - 1 + k;
        if (tt >= 0 && tt < T_TOK) {
            bf16x8 v = *(const bf16x8*)(xz + (size_t)tt * EDIM + e0 + e8);
            float4 w0 = *(const float4*)(W + k * EDIM + e0 + e8);
            float4 w1 = *(const float4*)(W + k * EDIM + e0 + e8 + 4);
            acc[0] += (float)v[0] * w0.x; acc[1] += (float)v[1] * w0.y;
            acc[2] += (float)v[2] * w0.z; acc[3] += (float)v[3] * w0.w;
            acc[4] += (float)v[4] * w1.x; acc[5] += (float)v[5] * w1.y;
            acc[6] += (float)v[6] * w1.z; acc[7] += (float)v[7] * w1.w;
        }
    }
    bf16x8 o;
#pragma unroll
    for (int j = 0; j < 8; ++j) {
        float s = acc[j];
        o[j] = (__bf16)(s / (1.f + __expf(-s)));
    }
    *(bf16x8*)(xc + (size_t)t * EDIM + e0 + e8) = o;
    *(bf16x8*)&s_t[tl][e8] = o;
    __syncthreads();
    {
        int el = tid >> 2, t8 = (tid & 3) * 8;
        bf16x8 o2;
#pragma unroll
        for (int j = 0; j < 8; ++j) o2[j] = s_t[t8 + j][el];
        *(bf16x8*)(xcT + (size_t)(e0 + el) * T_TOK + t0 + t8) = o2;
    }
}

// ---------------------------------------------------------------- scan
// bc layout (f32, plane-split): bc[t*128 + n] = B[t,n], bc[t*128+64+n] = C[t,n].

// Pass 1: block = 8 waves, 32 channels, one chunk; B-plane only staged.
// Wave w: 4 channels (w*4+g, g=lane>>4), 16 lanes/channel, 4 states/lane.
__global__ __launch_bounds__(512)
void scan1_kernel(const float* __restrict__ dtT, const __bf16* __restrict__ xcT,
                  const float* __restrict__ bc2, const float* __restrict__ A_log,
                  float* __restrict__ hend, float* __restrict__ dAp)
{
    __shared__ float  s_b[CKLEN * 64];     // 16 KB (B-plane)
    __shared__ float  s_dt[32][68];        // padded rows
    __shared__ __bf16 s_x[32][72];         // padded rows
    const int tid = threadIdx.x;
    const int lane = tid & 63, w = tid >> 6;
    const int g = lane >> 4, i = lane & 15;
    const int ck = blockIdx.x & (NCHUNK - 1);
    const int eg = (blockIdx.x >> 5) * 32;

    {
#pragma unroll
        for (int r = 0; r < 2; ++r) {
            int linear = r * 512 + tid;
            int t = linear >> 4, k = linear & 15;
            *(float4*)&s_b[t * 64 + 4 * k] =
                *(const float4*)(bc2 + (size_t)(ck * CKLEN + t) * 128 + 4 * k);
        }
        { int ch = tid >> 4, k = tid & 15;
          *(float4*)&s_dt[ch][4 * k] =
              *(const float4*)(dtT + (size_t)(eg + ch) * T_TOK + ck * CKLEN + 4 * k); }
        if (tid < 256) { int ch = tid >> 3, k = tid & 7;
          *(bf16x8*)&s_x[ch][8 * k] =
              *(const bf16x8*)(xcT + (size_t)(eg + ch) * T_TOK + ck * CKLEN + 8 * k); }
    }
    __syncthreads();

    const int ch = w * 4 + g;
    const int e = eg + ch;
    float4 al4 = *(const float4*)(A_log + 4 * i);
    const f32x2 A01 = {-__expf(al4.x), -__expf(al4.y)};
    const f32x2 A23 = {-__expf(al4.z), -__expf(al4.w)};
    f32x2 h01 = {0.f, 0.f}, h23 = {0.f, 0.f};
    float D = 0.f;

#pragma unroll 2
    for (int t0 = 0; t0 < CKLEN; t0 += 8) {
        float4 da = *(const float4*)&s_dt[ch][t0];
        float4 db = *(const float4*)&s_dt[ch][t0 + 4];
        bf16x8 x8 = *(const bf16x8*)&s_x[ch][t0];
        float dtv[8] = {da.x, da.y, da.z, da.w, db.x, db.y, db.z, db.w};
#pragma unroll
        for (int j = 0; j < 8; ++j) {
            float4 b0 = *(const float4*)&s_b[(t0 + j) * 64 + 4 * i];
            float dt = dtv[j];
            float u = dt * (float)x8[j];
            f32x2 dt2 = {dt, dt};
            f32x2 dA01 = exps2(dt2 * A01);
            f32x2 dA23 = exps2(dt2 * A23);
            f32x2 uu = {u, u};
            h01 = vfma2(dA01, h01, uu * (f32x2){b0.x, b0.y});
            h23 = vfma2(dA23, h23, uu * (f32x2){b0.z, b0.w});
            D += dt;
        }
    }
    const float L2E = 1.44269504f;
    size_t idx = ((size_t)e * NCHUNK + ck) * 64 + 4 * i;
    *(float4*)(hend + idx) = make_float4(h01.x, h01.y, h23.x, h23.y);
    *(float4*)(dAp + idx)  = make_float4(__builtin_amdgcn_exp2f(A01.x * L2E * D),
                                         __builtin_amdgcn_exp2f(A01.y * L2E * D),
                                         __builtin_amdgcn_exp2f(A23.x * L2E * D),
                                         __builtin_amdgcn_exp2f(A23.y * L2E * D));
}

// Mid: serial scan over chunk summaries -> h_start per chunk, IN PLACE over hend.
__global__ __launch_bounds__(256)
void scan_mid_kernel(float* __restrict__ hend_h0, const float* __restrict__ dAp)
{
    int gid = blockIdx.x * 256 + threadIdx.x;     // over E*64
    int e = gid >> 6, n = gid & 63;
    float h = 0.f;
#pragma unroll
    for (int ck = 0; ck < NCHUNK; ++ck) {
        size_t idx = ((size_t)e * NCHUNK + ck) * 64 + n;
        float he = hend_h0[idx];
        float P  = dAp[idx];
        hend_h0[idx] = h;
        h = P * h + he;
    }
}

// Pass 2: block = 8 waves, 32 channels, one chunk; B/C planes staged separately.
__global__ __launch_bounds__(512)
void scan2_kernel(const float* __restrict__ dtT, const __bf16* __restrict__ xcT,
                  const __bf16* __restrict__ szT, const float* __restrict__ bc2,
                  const float* __restrict__ A_log, const float* __restrict__ h0s,
                  __bf16* __restrict__ y)
{
    __shared__ float  s_bp[CKLEN * 64];    // 16 KB (B-plane)
    __shared__ float  s_cp[CKLEN * 64];    // 16 KB (C-plane)
    __shared__ float  s_dt[32][68];        // padded rows
    __shared__ __bf16 s_x[32][72];         // padded rows
    __shared__ __bf16 s_y[CKLEN][36];      // padded, t-major tile
    const int tid = threadIdx.x;
    const int lane = tid & 63, w = tid >> 6;
    const int g = lane >> 4, i = lane & 15;
    const int ck = blockIdx.x & (NCHUNK - 1);
    const int eg = (blockIdx.x >> 5) * 32;

    {
#pragma unroll
        for (int r = 0; r < 2; ++r) {
            int linear = r * 512 + tid;
            int t = linear >> 4, k = linear & 15;
            const float* src = bc2 + (size_t)(ck * CKLEN + t) * 128 + 4 * k;
            *(float4*)&s_bp[t * 64 + 4 * k] = *(const float4*)src;
            *(float4*)&s_cp[t * 64 + 4 * k] = *(const float4*)(src + 64);
        }
        { int ch = tid >> 4, k = tid & 15;
          *(float4*)&s_dt[ch][4 * k] =
              *(const float4*)(dtT + (size_t)(eg + ch) * T_TOK + ck * CKLEN + 4 * k); }
        if (tid < 256) { int ch = tid >> 3, k = tid & 7;
          *(bf16x8*)&s_x[ch][8 * k] =
              *(const bf16x8*)(xcT + (size_t)(eg + ch) * T_TOK + ck * CKLEN + 8 * k); }
    }
    __syncthreads();

    const int ch = w * 4 + g;
    const int e = eg + ch;
    float4 al4 = *(const float4*)(A_log + 4 * i);
    const f32x2 A01 = {-__expf(al4.x), -__expf(al4.y)};
    const f32x2 A23 = {-__expf(al4.z), -__expf(al4.w)};
    float4 hh = *(const float4*)(h0s + ((size_t)e * NCHUNK + ck) * 64 + 4 * i);
    f32x2 h01 = {hh.x, hh.y}, h23 = {hh.z, hh.w};

#pragma unroll 2
    for (int t0 = 0; t0 < CKLEN; t0 += 8) {
        float4 da = *(const float4*)&s_dt[ch][t0];
        float4 db = *(const float4*)&s_dt[ch][t0 + 4];
        bf16x8 x8 = *(const bf16x8*)&s_x[ch][t0];
        float dtv[8] = {da.x, da.y, da.z, da.w, db.x, db.y, db.z, db.w};
#pragma unroll
        for (int j = 0; j < 8; ++j) {
            float4 b0 = *(const float4*)&s_bp[(t0 + j) * 64 + 4 * i];
            float4 c0 = *(const float4*)&s_cp[(t0 + j) * 64 + 4 * i];
            float dt = dtv[j];
            float u = dt * (float)x8[j];
            f32x2 dt2 = {dt, dt};
            f32x2 dA01 = exps2(dt2 * A01);
            f32x2 dA23 = exps2(dt2 * A23);
            f32x2 uu = {u, u};
            h01 = vfma2(dA01, h01, uu * (f32x2){b0.x, b0.y});
            h23 = vfma2(dA23, h23, uu * (f32x2){b0.z, b0.w});
            f32x2 pp = h01 * (f32x2){c0.x, c0.y};
            pp = vfma2(h23, (f32x2){c0.z, c0.w}, pp);
            float p = pp.x + pp.y;
            p = dpp_sum16(p);
            if (i == 15) s_y[t0 + j][ch] = (__bf16)p;
        }
    }
    __syncthreads();

    {
        int tt = tid >> 3, q = tid & 7;
        bf16x4 o;
#pragma unroll
        for (int d = 0; d < 4; ++d) {
            float zv = (float)szT[(size_t)(eg + 4 * q + d) * T_TOK + ck * CKLEN + tt];
            o[d] = (__bf16)((float)s_y[tt][4 * q + d] * zv);
        }
        *(bf16x4*)(y + (size_t)(ck * CKLEN + tt) * EDIM + eg + 4 * q) = o;
    }
}

// ---------------------------------------------------------------- GEMM common
__device__ __forceinline__ void glds16(const __bf16* g, __bf16* l)
{
    __builtin_amdgcn_global_load_lds(
        (const __attribute__((address_space(1))) unsigned*)g,
        (__attribute__((address_space(3))) unsigned*)l, 16, 0, 0);
}

template<int EPI>
__device__ __forceinline__ void gemm_epilogue(
    const f32x4& a, int row, int col, int N,
    void* Cout, void* Cout2, const float* res)
{
    if (EPI == 1) {
#pragma unroll
        for (int i = 0; i < 4; ++i)
            ((__bf16*)Cout)[(size_t)(row + i) * N + col] = (__bf16)a[i];
    } else if (EPI == 2) {
#pragma unroll
        for (int i = 0; i < 4; ++i) {
            size_t off = (size_t)(row + i) * N + col;
            ((float*)Cout)[off] = a[i] + res[off];
        }
    } else if (EPI == 3) {
        if (col < 2048) {
            float bias = res[col];
            float4 v;
            float* vv = (float*)&v;
#pragma unroll
            for (int i = 0; i < 4; ++i) {
                float s = a[i] + bias;
                s = (s > 20.f) ? s : log1pf(__expf(s));
                vv[i] = fminf(fmaxf(s, 0.001f), 0.1f);
            }
            *(float4*)((float*)Cout + (size_t)col * T_TOK + row) = v;
        } else {
#pragma unroll
            for (int i = 0; i < 4; ++i)
                ((float*)Cout2)[(size_t)(row + i) * 128 + (col - 2048)] = a[i];
        }
    } else if (EPI == 4) {
        if (col < 2048) {
#pragma unroll
            for (int i = 0; i < 4; ++i)
                ((__bf16*)Cout)[(size_t)(row + i) * EDIM + col] = (__bf16)a[i];
        } else {
            bf16x4 v;
#pragma unroll
            for (int i = 0; i < 4; ++i) {
                float s = a[i];
                v[i] = (__bf16)(s / (1.f + __expf(-s)));
            }
            *(bf16x4*)((__bf16*)Cout2 + (size_t)(col - 2048) * T_TOK + row) = v;
        }
    }
}

// 4-wave GEMM: 64 x TN tile (TN = 64 or 128), BK=64, 2-phase,
// 8-chunk XOR-swizzled LDS.  SWZ<1>: XCD-contiguous block remap.
template<int EPI, int TN, int SWZ>
__global__ __launch_bounds__(256)
void gemm_kernel(const __bf16* __restrict__ A, const __bf16* __restrict__ Bt,
                 void* __restrict__ Cout, void* __restrict__ Cout2,
                 const float* __restrict__ res, int M, int N, int K)
{
    constexpr int NF = TN / 32;            // n-frags per wave
    constexpr int BQ = TN / 32;            // B glds16 per wave per stage
    __shared__ __bf16 sAl[2 * 64 * 64];    // 16 KB
    __shared__ __bf16 sBl[2 * TN * 64];    // 16 or 32 KB
    const int t = threadIdx.x;
    const int wave = t >> 6, lane = t & 63;
    int bx = blockIdx.x, by = blockIdx.y;
    if (SWZ) {
        int nwg = gridDim.x * gridDim.y;
        int bid = by * gridDim.x + bx;
        int cpx = nwg >> 3;
        int swz = (bid & 7) * cpx + (bid >> 3);
        bx = swz % gridDim.x;
        by = swz / gridDim.x;
    }
    const int brow = by * 64, bcol = bx * TN;
    const int wr = (wave >> 1) * 32, wc = (wave & 1) * (TN / 2);
    f32x4 acc[2][NF] = {};

    const int rl8 = lane >> 3;
    const int ck8 = (lane & 7) ^ rl8;
    const __bf16* gA = A  + (size_t)(brow + wave * 16 + rl8) * K + ck8 * 8;
    const __bf16* gB = Bt + (size_t)(bcol + wave * (TN / 4) + rl8) * K + ck8 * 8;

    auto stage = [&](int buf, int k0) {
        __bf16* ba = sAl + buf * (64 * 64) + (wave * 16) * 64;
        __bf16* bb = sBl + buf * (TN * 64) + (wave * (TN / 4)) * 64;
#pragma unroll
        for (int q = 0; q < 2; ++q)
            glds16(gA + (size_t)(q * 8) * K + k0, ba + q * 8 * 64);
#pragma unroll
        for (int q = 0; q < BQ; ++q)
            glds16(gB + (size_t)(q * 8) * K + k0, bb + q * 8 * 64);
    };

    stage(0, 0);
    int cur = 0;
    for (int k0 = 0; k0 < K; k0 += 64) {
        __syncthreads();
        if (k0 + 64 < K) stage(cur ^ 1, k0 + 64);
        const __bf16* At = sAl + cur * (64 * 64);
        const __bf16* Btl = sBl + cur * (TN * 64);
#pragma unroll
        for (int ks = 0; ks < 2; ++ks) {
            const int rc = (((ks * 4 + (lane >> 4)) ^ (lane & 7))) * 8;
            bf16x8 af[2], bg[NF];
#pragma unroll
            for (int m = 0; m < 2; ++m)
                af[m] = *(const bf16x8*)&At[(wr + m * 16 + (lane & 15)) * 64 + rc];
#pragma unroll
            for (int n = 0; n < NF; ++n)
                bg[n] = *(const bf16x8*)&Btl[(wc + n * 16 + (lane & 15)) * 64 + rc];
#pragma unroll
            for (int m = 0; m < 2; ++m)
#pragma unroll
                for (int n = 0; n < NF; ++n)
                    acc[m][n] = __builtin_amdgcn_mfma_f32_16x16x32_bf16(
                        af[m], bg[n], acc[m][n], 0, 0, 0);
        }
        cur ^= 1;
    }

    const int c_l = lane & 15, r_l = (lane >> 4) * 4;
#pragma unroll
    for (int m = 0; m < 2; ++m)
#pragma unroll
        for (int n = 0; n < NF; ++n)
            gemm_epilogue<EPI>(acc[m][n], brow + wr + m * 16 + r_l,
                               bcol + wc + n * 16 + c_l, N, Cout, Cout2, res);
}

// 8-wave big GEMM: 128 x 128 tile, BK=64, 2-phase, XOR chunk-swizzled LDS.
// 64 KB LDS -> 2 blocks/CU (16 waves) so barrier vmcnt drains cross-hide.
// Wave layout 2x4: wave-tile 64x32 (acc[4][2], 16 MFMA/wave/K-step).
// EPI 5: fused GLU (16-col interleaved gate/up weights): frag pair (0,1)
// within a wave = gate/up cols for the same 32-col group.
// SWZ<1>: XCD-contiguous block remap (grid mult of 8).
template<int EPI, int SWZ>
__global__ __launch_bounds__(512)
void gemm_big(const __bf16* __restrict__ A, const __bf16* __restrict__ Bt,
              void* __restrict__ Cout, void* __restrict__ Cout2,
              const float* __restrict__ res, int M, int N, int K)
{
    __shared__ __bf16 sAl[2 * 128 * 64];   // 32 KB
    __shared__ __bf16 sBl[2 * 128 * 64];   // 32 KB
    const int t = threadIdx.x;
    const int w = t >> 6, lane = t & 63;
    int bx = blockIdx.x, by = blockIdx.y;
    if (SWZ) {
        int nwg = gridDim.x * gridDim.y;
        int bid = by * gridDim.x + bx;
        int cpx = nwg >> 3;
        int swz = (bid & 7) * cpx + (bid >> 3);
        bx = swz % gridDim.x;
        by = swz / gridDim.x;
    }
    const int brow = by * 128, bcol = bx * 128;
    const int wr = (w >> 2) * 64, wc = (w & 3) * 32;
    f32x4 acc[4][2] = {};

    const int rl8 = lane >> 3;
    const int ck8 = (lane & 7) ^ rl8;
    const __bf16* gA = A  + (size_t)(brow + w * 16 + rl8) * K + ck8 * 8;
    const __bf16* gB = Bt + (size_t)(bcol + w * 16 + rl8) * K + ck8 * 8;

    auto stage = [&](int buf, int k0) {
        __bf16* ba = sAl + buf * (128 * 64) + (w * 16) * 64;
        __bf16* bb = sBl + buf * (128 * 64) + (w * 16) * 64;
#pragma unroll
        for (int q = 0; q < 2; ++q)
            glds16(gA + (size_t)(q * 8) * K + k0, ba + q * 8 * 64);
#pragma unroll
        for (int q = 0; q < 2; ++q)
            glds16(gB + (size_t)(q * 8) * K + k0, bb + q * 8 * 64);
    };

    stage(0, 0);
    int cur = 0;
    for (int k0 = 0; k0 < K; k0 += 64) {
        __syncthreads();
        if (k0 + 64 < K) stage(cur ^ 1, k0 + 64);
        const __bf16* At = sAl + cur * (128 * 64);
        const __bf16* Btl = sBl + cur * (128 * 64);
#pragma unroll
        for (int ks = 0; ks < 2; ++ks) {
            const int rchk = (((ks * 4 + (lane >> 4)) ^ (lane & 7))) * 8;
            bf16x8 af[4], bg[2];
#pragma unroll
            for (int m = 0; m < 4; ++m)
                af[m] = *(const bf16x8*)&At[(wr + m * 16 + (lane & 15)) * 64 + rchk];
#pragma unroll
            for (int n = 0; n < 2; ++n)
                bg[n] = *(const bf16x8*)&Btl[(wc + n * 16 + (lane & 15)) * 64 + rchk];
#pragma unroll
            for (int m = 0; m < 4; ++m)
#pragma unroll
                for (int n = 0; n < 2; ++n)
                    acc[m][n] = __builtin_amdgcn_mfma_f32_16x16x32_bf16(
                        af[m], bg[n], acc[m][n], 0, 0, 0);
        }
        cur ^= 1;
    }

    const int c_l = lane & 15, r_l = (lane >> 4) * 4;
    if constexpr (EPI == 5) {
#pragma unroll
        for (int m = 0; m < 4; ++m) {
            int row = brow + wr + m * 16 + r_l;
            int fcol = (((bcol + wc) >> 5) << 4) + c_l;
#pragma unroll
            for (int i = 0; i < 4; ++i) {
                float gg = acc[m][0][i];
                float uu = acc[m][1][i];
                ((__bf16*)Cout)[(size_t)(row + i) * 2048 + fcol] =
                    (__bf16)(gg / (1.f + __expf(-gg)) * uu);
            }
        }
    } else {
#pragma unroll
        for (int m = 0; m < 4; ++m)
#pragma unroll
            for (int n = 0; n < 2; ++n)
                gemm_epilogue<EPI>(acc[m][n], brow + wr + m * 16 + r_l,
                                   bcol + wc + n * 16 + c_l, N, Cout, Cout2, res);
    }
}

// ---------------------------------------------------------------- launch
extern "C" void kernel_launch(void* const* d_in, const int* in_sizes, int n_in,
                              void* d_out, int out_size, void* d_ws, size_t ws_size,
                              hipStream_t stream)
{
    (void)in_sizes; (void)n_in; (void)out_size; (void)ws_size;
    const float* x     = (const float*)d_in[0];
    const float* inw   = (const float*)d_in[1];
    const float* ffnw  = (const float*)d_in[2];
    const float* inpW  = (const float*)d_in[3];
    const float* convW = (const float*)d_in[4];
    const float* convB = (const float*)d_in[5];
    const float* dtW   = (const float*)d_in[6];
    const float* dtB   = (const float*)d_in[7];
    const float* BW    = (const float*)d_in[8];
    const float* CW    = (const float*)d_in[9];
    const float* Alog  = (const float*)d_in[10];
    const float* outpW = (const float*)d_in[11];
    const float* gateW = (const float*)d_in[12];
    const float* upW   = (const float*)d_in[13];
    const float* downW = (const float*)d_in[14];
    float* out = (float*)d_out;

    char* p = (char*)d_ws;
    auto alloc = [&](size_t n) { char* q = p; p += (n + 255) & ~(size_t)255; return q; };
    __bf16* wt_inproj = (__bf16*)alloc(4096ull * 1024 * 2);
    __bf16* wt_dtbc   = (__bf16*)alloc(2176ull * 2048 * 2);  // rows: 0-2047 dt, 2048-2111 B, 2112-2175 C
    __bf16* wt_outp   = (__bf16*)alloc(1024ull * 2048 * 2);
    __bf16* wt_gu     = (__bf16*)alloc(4096ull * 1024 * 2);  // 16-col interleaved gate/up
    __bf16* wt_down   = (__bf16*)alloc(1024ull * 2048 * 2);
    __bf16* normed    = (__bf16*)alloc(2048ull * 1024 * 2);  // reused as n2
    __bf16* xz        = (__bf16*)alloc(2048ull * 2048 * 2);  // x_z half of in_proj
    __bf16* gu_buf    = (__bf16*)alloc(2048ull * 4096 * 2);  // dAp scratch
    __bf16* xc        = (__bf16*)alloc(2048ull * 2048 * 2);  // conv out, reused as y
    float*  scratch16 = (float*)alloc(2048ull * 2048 * 4);   // hend/h0 then ffnmid
    float*  bc        = (float*)alloc(2048ull * 128 * 4);
    float*  dtT       = (float*)alloc(2048ull * 2048 * 4);
    __bf16* xcT       = (__bf16*)alloc(2048ull * 2048 * 2);
    __bf16* szT       = (__bf16*)alloc(2048ull * 2048 * 2);
    float*  x2        = (float*)alloc(2048ull * 1024 * 4);

    dim3 B256(256);
    // batched weight prep (one dispatch); gate/up interleaved at 16-col granularity
    {
        TJobs8 tj;
        int off = 0, ji = 0;
        auto addjob = [&](const float* s, __bf16* d, int R, int C, int S, int mode) {
            tj.j[ji++] = TJob{s, d, R, C, S, C / 32, off, mode};
            off += (C / 32) * (R / 32);
        };
        addjob(inpW,  wt_inproj, 1024, 4096, 4096, 0);
        addjob(dtW,   wt_dtbc,   2048, 2048, 2048, 0);
        addjob(BW,    wt_dtbc + 2048ull * 2048, 2048, 64, 64, 0);
        addjob(CW,    wt_dtbc + 2112ull * 2048, 2048, 64, 64, 0);
        addjob(outpW, wt_outp,   2048, 1024, 1024, 0);
        addjob(gateW, wt_gu,     1024, 2048, 2048, 1);
        addjob(upW,   wt_gu,     1024, 2048, 2048, 2);
        addjob(downW, wt_down,   2048, 1024, 1024, 0);
        wprep_kernel<<<dim3(off), B256, 0, stream>>>(tj);
    }

    // normed = rmsnorm(x, inw)
    rmsnorm_kernel<<<dim3(2048), B256, 0, stream>>>(x, inw, normed);
    // in_proj: xz (t-major bf16) + szT (silu'd z, channel-major)
    gemm_big<4, 1><<<dim3(32, 16), dim3(512), 0, stream>>>(normed, wt_inproj, xz, szT, nullptr, 2048, 4096, 1024);
    // xc = silu(conv(xz) + b), also writes xcT (channel-major) in one pass
    conv_silu_xt_kernel<<<dim3(32, 64), B256, 0, stream>>>(xz, convW, convB, xc, xcT);
    // fused dt+bc: dtT (softplus'd, channel-major f32) + bc (t-major f32, planes)
    gemm_kernel<3, 128, 1><<<dim3(17, 32), B256, 0, stream>>>(xc, wt_dtbc, dtT, bc, dtB, 2048, 2176, 2048);

    // chunked SSM scan
    float* hend = scratch16;                      // 16 MB (E*32*64 f32)
    float* dAp  = (float*)gu_buf;                 // 16 MB
    scan1_kernel<<<dim3(2048), dim3(512), 0, stream>>>(dtT, xcT, bc, Alog, hend, dAp);
    scan_mid_kernel<<<dim3(512), B256, 0, stream>>>(hend, dAp);
    __bf16* y = xc;                               // xc dead after dt GEMM
    scan2_kernel<<<dim3(2048), dim3(512), 0, stream>>>(dtT, xcT, szT, bc, Alog, hend, y);

    // x2 = x + y @ out_proj
    gemm_kernel<2, 64, 1><<<dim3(16, 32), B256, 0, stream>>>(y, wt_outp, x2, nullptr, x, 2048, 1024, 2048);
    // n2 = rmsnorm(x2, ffnw)
    rmsnorm_kernel<<<dim3(2048), B256, 0, stream>>>(x2, ffnw, normed);
    // ffnmid = silu(n2@gate) * (n2@up)  -- fused GLU epilogue
    __bf16* ffnmid = (__bf16*)scratch16;
    gemm_big<5, 1><<<dim3(32, 16), dim3(512), 0, stream>>>(normed, wt_gu, ffnmid, nullptr, nullptr, 2048, 4096, 1024);
    // out = x2 + ffnmid @ down
    gemm_kernel<2, 64, 1><<<dim3(16, 32), B256, 0, stream>>>(ffnmid, wt_down, out, nullptr, x2, 2048, 1024, 2048);
}